// Round 1
// baseline (273.324 us; speedup 1.0000x reference)
//
#include <hip/hip_runtime.h>
#include <hip/hip_bf16.h>

#define B_SZ 4096
#define L_SZ 200

// ---------------------------------------------------------------------------
// K0: init workspace accumulators (ws is poisoned 0xAA before every launch)
// ---------------------------------------------------------------------------
__global__ void k_init(int* __restrict__ first_bad, float* __restrict__ acc) {
    int t = threadIdx.x;
    if (t == 0) first_bad[0] = B_SZ;
    if (t < 768) acc[t] = 0.f;
}

// ---------------------------------------------------------------------------
// K0b: row-halt semantics — first row b whose history[b][0]==0 halts the loop
// ---------------------------------------------------------------------------
__global__ void k_firstbad(const int* __restrict__ history, int* __restrict__ first_bad) {
    int b = threadIdx.x + blockIdx.x * blockDim.x;
    if (b < B_SZ && history[(size_t)b * L_SZ] == 0) atomicMin(first_bad, b);
}

// ---------------------------------------------------------------------------
// K1: per-row masked mean-pool of concat(item_emb, cate_emb) + build x[b,384]
// one block (256 thr) per batch row; 8 groups of 32 lanes gather 2x256B rows
// ---------------------------------------------------------------------------
__global__ __launch_bounds__(256) void k_pool(
    const int* __restrict__ user, const int* __restrict__ item,
    const int* __restrict__ history, const int* __restrict__ cate_list,
    const float* __restrict__ user_W, const float* __restrict__ item_W,
    const float* __restrict__ cate_W, const int* __restrict__ first_bad,
    float* __restrict__ x)
{
    const int b = blockIdx.x;
    const int tid = threadIdx.x;
    __shared__ int sh_hist[L_SZ];
    __shared__ int s_fz;
    __shared__ __align__(16) float red[8][128];
    if (tid == 0) s_fz = L_SZ;
    __syncthreads();
    if (tid < L_SZ) {
        int h = history[(size_t)b * L_SZ + tid];
        sh_hist[tid] = h;
        if (tid >= 1 && h == 0) atomicMin(&s_fz, tid);
    }
    __syncthreads();
    const bool active = (b < first_bad[0]);
    const int valid = active ? s_fz : 0;          // == sum(mask[b,:])
    const float inv_cnt = 1.0f / (float)max(valid, 1);

    const int group = tid >> 5, lane = tid & 31;
    const int sub = lane >> 4, q = lane & 15;     // sub 0: item table, 1: cate table
    float4 acc = make_float4(0.f, 0.f, 0.f, 0.f);
    for (int l = group; l < valid; l += 8) {
        int id = sh_hist[l];
        const float* row = (sub == 0) ? (item_W + (size_t)id * 64)
                                      : (cate_W + (size_t)cate_list[id] * 64);
        float4 v = ((const float4*)row)[q];
        acc.x += v.x; acc.y += v.y; acc.z += v.z; acc.w += v.w;
    }
    *((float4*)&red[group][lane * 4]) = acc;
    __syncthreads();

    float* xrow = x + (size_t)b * 384;
    if (tid < 128) {
        float s = 0.f;
        #pragma unroll
        for (int g = 0; g < 8; ++g) s += red[g][tid];
        xrow[256 + tid] = s * inv_cnt;                              // pooled
        xrow[tid] = user_W[(size_t)user[b] * 128 + tid];            // user emb
    } else if (tid < 192) {
        int f = tid - 128;
        xrow[128 + f] = item_W[(size_t)item[b] * 64 + f];           // item emb
    } else {
        int f = tid - 192;
        xrow[192 + f] = cate_W[(size_t)cate_list[item[b]] * 64 + f];// item's cate emb
    }
}

// ---------------------------------------------------------------------------
// K2a: BN batch statistics partial sums (coalesced column ownership)
// 32 blocks x 384 threads, 128 rows each; atomicAdd partials to acc[768]
// ---------------------------------------------------------------------------
__global__ __launch_bounds__(384) void k_bnstats(const float* __restrict__ x,
                                                 float* __restrict__ acc) {
    const int f = threadIdx.x;          // 0..383
    const int r0 = blockIdx.x * 128;
    float s = 0.f, s2 = 0.f;
    for (int r = r0; r < r0 + 128; ++r) {
        float v = x[(size_t)r * 384 + f];
        s += v; s2 += v * v;
    }
    atomicAdd(&acc[f], s);
    atomicAdd(&acc[384 + f], s2);
}

// ---------------------------------------------------------------------------
// K2b: finalize BN -> per-feature affine  y = x*A + C
// ---------------------------------------------------------------------------
__global__ void k_bnfinal(const float* __restrict__ acc,
                          const float* __restrict__ gamma,
                          const float* __restrict__ beta,
                          float* __restrict__ A, float* __restrict__ C) {
    int f = threadIdx.x;
    if (f < 384) {
        const float inv_b = 1.0f / (float)B_SZ;
        float mean = acc[f] * inv_b;
        float var  = acc[384 + f] * inv_b - mean * mean;
        float a = gamma[f] * rsqrtf(var + 1e-5f);
        A[f] = a;
        C[f] = beta[f] - mean * a;
    }
}

// ---------------------------------------------------------------------------
// K3: fused MLP: (x*A+C) @ W1^T +b1 -> prelu -> @W2^T +b2 -> prelu -> @W3^T +b3
//     -> softmax(2).  16 rows per 256-thread block; x,h1,h2 in padded LDS.
// ---------------------------------------------------------------------------
__global__ __launch_bounds__(256) void k_mlp(
    const float* __restrict__ x, const float* __restrict__ A, const float* __restrict__ C,
    const float* __restrict__ W1, const float* __restrict__ b1, const float* __restrict__ a1p,
    const float* __restrict__ W2, const float* __restrict__ b2, const float* __restrict__ a2p,
    const float* __restrict__ W3, const float* __restrict__ b3,
    float* __restrict__ out)
{
    const int r0 = blockIdx.x * 16;
    const int tid = threadIdx.x;
    const int rr = tid & 15, og = tid >> 4;
    __shared__ __align__(16) float xs[16][388];   // 384 + 4 pad (bank spread, 16B align)
    __shared__ __align__(16) float h1[16][204];   // 200 + 4 pad
    __shared__ __align__(16) float h2[16][84];    // 80 + 4 pad

    // load 16 rows of x, apply BN affine during load (coalesced: e is contiguous)
    for (int e = tid; e < 16 * 384; e += 256) {
        int rr2 = e / 384, f = e - rr2 * 384;
        xs[rr2][f] = x[(size_t)r0 * 384 + e] * A[f] + C[f];
    }
    __syncthreads();

    const float a1 = a1p[0], a2 = a2p[0];

    // layer 1: 384 -> 200
    #pragma unroll
    for (int k = 0; k < 13; ++k) {
        int o = og + 16 * k;
        if (o < 200) {
            const float4* wrow = (const float4*)(W1 + (size_t)o * 384);
            const float4* xr   = (const float4*)&xs[rr][0];
            float s = 0.f;
            #pragma unroll 4
            for (int f4 = 0; f4 < 96; ++f4) {
                float4 w = wrow[f4], v = xr[f4];
                s += w.x * v.x + w.y * v.y + w.z * v.z + w.w * v.w;
            }
            s += b1[o];
            h1[rr][o] = (s >= 0.f) ? s : a1 * s;
        }
    }
    __syncthreads();

    // layer 2: 200 -> 80
    #pragma unroll
    for (int k = 0; k < 5; ++k) {
        int o = og + 16 * k;
        const float4* wrow = (const float4*)(W2 + (size_t)o * 200);
        const float4* hr   = (const float4*)&h1[rr][0];
        float s = 0.f;
        #pragma unroll 5
        for (int f4 = 0; f4 < 50; ++f4) {
            float4 w = wrow[f4], v = hr[f4];
            s += w.x * v.x + w.y * v.y + w.z * v.z + w.w * v.w;
        }
        s += b2[o];
        h2[rr][o] = (s >= 0.f) ? s : a2 * s;
    }
    __syncthreads();

    // layer 3: 80 -> 2, then softmax
    if (tid < 16) {
        float l0 = b3[0], l1 = b3[1];
        #pragma unroll 8
        for (int f = 0; f < 80; ++f) {
            float h = h2[tid][f];
            l0 += h * W3[f];
            l1 += h * W3[80 + f];
        }
        float m = fmaxf(l0, l1);
        float e0 = expf(l0 - m), e1 = expf(l1 - m);
        float inv = 1.0f / (e0 + e1);
        out[(size_t)(r0 + tid) * 2 + 0] = e0 * inv;
        out[(size_t)(r0 + tid) * 2 + 1] = e1 * inv;
    }
}

// ---------------------------------------------------------------------------
extern "C" void kernel_launch(void* const* d_in, const int* in_sizes, int n_in,
                              void* d_out, int out_size, void* d_ws, size_t ws_size,
                              hipStream_t stream) {
    const int*   user      = (const int*)  d_in[0];
    const int*   item      = (const int*)  d_in[1];
    const int*   history   = (const int*)  d_in[2];
    /* d_in[3] = length (unused: derived from history zeros, matching ref) */
    const int*   cate_list = (const int*)  d_in[4];
    const float* user_W    = (const float*)d_in[5];
    const float* item_W    = (const float*)d_in[6];
    const float* cate_W    = (const float*)d_in[7];
    const float* gamma     = (const float*)d_in[8];
    const float* beta      = (const float*)d_in[9];
    const float* W1        = (const float*)d_in[10];
    const float* b1        = (const float*)d_in[11];
    const float* a1        = (const float*)d_in[12];
    const float* W2        = (const float*)d_in[13];
    const float* b2        = (const float*)d_in[14];
    const float* a2        = (const float*)d_in[15];
    const float* W3        = (const float*)d_in[16];
    const float* b3        = (const float*)d_in[17];
    float* out = (float*)d_out;

    // workspace layout (floats): [0..3] first_bad(int)+pad, [16..783] acc,
    // [784..1167] A, [1168..1551] C, [1552..] x[4096*384]
    int*   first_bad = (int*)d_ws;
    float* acc = (float*)d_ws + 16;
    float* A   = acc + 768;
    float* C   = A + 384;
    float* x   = C + 384;

    hipLaunchKernelGGL(k_init,     dim3(1),    dim3(768), 0, stream, first_bad, acc);
    hipLaunchKernelGGL(k_firstbad, dim3(16),   dim3(256), 0, stream, history, first_bad);
    hipLaunchKernelGGL(k_pool,     dim3(B_SZ), dim3(256), 0, stream,
                       user, item, history, cate_list, user_W, item_W, cate_W,
                       first_bad, x);
    hipLaunchKernelGGL(k_bnstats,  dim3(32),   dim3(384), 0, stream, x, acc);
    hipLaunchKernelGGL(k_bnfinal,  dim3(1),    dim3(384), 0, stream, acc, gamma, beta, A, C);
    hipLaunchKernelGGL(k_mlp,      dim3(B_SZ/16), dim3(256), 0, stream,
                       x, A, C, W1, b1, a1, W2, b2, a2, W3, b3, out);
}

// Round 2
// 250.766 us; speedup vs baseline: 1.0900x; 1.0900x over previous
//
#include <hip/hip_runtime.h>
#include <hip/hip_bf16.h>

#define B_SZ 4096
#define L_SZ 200

// ---------------------------------------------------------------------------
// K0: init workspace accumulators (ws is poisoned 0xAA before every launch)
// ---------------------------------------------------------------------------
__global__ void k_init(int* __restrict__ first_bad, float* __restrict__ acc) {
    int t = threadIdx.x;
    if (t == 0) first_bad[0] = B_SZ;
    if (t < 768) acc[t] = 0.f;
}

// ---------------------------------------------------------------------------
// K0b: row-halt semantics — first row b whose history[b][0]==0 halts the loop
// ---------------------------------------------------------------------------
__global__ void k_firstbad(const int* __restrict__ history, int* __restrict__ first_bad) {
    int b = threadIdx.x + blockIdx.x * blockDim.x;
    if (b < B_SZ && history[(size_t)b * L_SZ] == 0) atomicMin(first_bad, b);
}

// ---------------------------------------------------------------------------
// K1: per-row masked mean-pool of concat(item_emb, cate_emb) + build x[b,384]
// one block (256 thr) per batch row; cate ids prefetched to break the
// id -> cate_list -> row serial chain; gather loop 2-way unrolled.
// ---------------------------------------------------------------------------
__global__ __launch_bounds__(256) void k_pool(
    const int* __restrict__ user, const int* __restrict__ item,
    const int* __restrict__ history, const int* __restrict__ cate_list,
    const float* __restrict__ user_W, const float* __restrict__ item_W,
    const float* __restrict__ cate_W, const int* __restrict__ first_bad,
    float* __restrict__ x)
{
    const int b = blockIdx.x;
    const int tid = threadIdx.x;
    __shared__ int sh_item[L_SZ];
    __shared__ int sh_cid[L_SZ];
    __shared__ int s_fz;
    __shared__ __align__(16) float red[8][128];
    if (tid == 0) s_fz = L_SZ;
    __syncthreads();
    if (tid < L_SZ) {
        int h = history[(size_t)b * L_SZ + tid];
        sh_item[tid] = h;
        if (tid >= 1 && h == 0) atomicMin(&s_fz, tid);
        sh_cid[tid] = cate_list[h];   // h in [0, ITEM_COUNT) always -> safe
    }
    __syncthreads();
    const bool active = (b < first_bad[0]);
    const int valid = active ? s_fz : 0;          // == sum(mask[b,:])
    const float inv_cnt = 1.0f / (float)max(valid, 1);

    const int group = tid >> 5, lane = tid & 31;
    const int sub = lane >> 4, q = lane & 15;     // sub 0: item table, 1: cate table
    const float* tab = (sub == 0) ? item_W : cate_W;
    const int*   ids = (sub == 0) ? sh_item : sh_cid;
    float4 acc = make_float4(0.f, 0.f, 0.f, 0.f);
    int l = group;
    for (; l + 8 < valid; l += 16) {
        int id0 = ids[l], id1 = ids[l + 8];
        float4 v0 = ((const float4*)(tab + (size_t)id0 * 64))[q];
        float4 v1 = ((const float4*)(tab + (size_t)id1 * 64))[q];
        acc.x += v0.x + v1.x; acc.y += v0.y + v1.y;
        acc.z += v0.z + v1.z; acc.w += v0.w + v1.w;
    }
    if (l < valid) {
        int id = ids[l];
        float4 v = ((const float4*)(tab + (size_t)id * 64))[q];
        acc.x += v.x; acc.y += v.y; acc.z += v.z; acc.w += v.w;
    }
    *((float4*)&red[group][lane * 4]) = acc;
    __syncthreads();

    float* xrow = x + (size_t)b * 384;
    if (tid < 128) {
        float s = 0.f;
        #pragma unroll
        for (int g = 0; g < 8; ++g) s += red[g][tid];
        xrow[256 + tid] = s * inv_cnt;                              // pooled
        xrow[tid] = user_W[(size_t)user[b] * 128 + tid];            // user emb
    } else if (tid < 192) {
        int f = tid - 128;
        xrow[128 + f] = item_W[(size_t)item[b] * 64 + f];           // item emb
    } else {
        int f = tid - 192;
        xrow[192 + f] = cate_W[(size_t)cate_list[item[b]] * 64 + f];// item's cate emb
    }
}

// ---------------------------------------------------------------------------
// K2a: BN batch statistics partial sums (coalesced column ownership)
// 128 blocks x 384 threads, 32 rows each; atomicAdd partials to acc[768]
// ---------------------------------------------------------------------------
__global__ __launch_bounds__(384) void k_bnstats(const float* __restrict__ x,
                                                 float* __restrict__ acc) {
    const int f = threadIdx.x;          // 0..383
    const int r0 = blockIdx.x * 32;
    float s = 0.f, s2 = 0.f;
    for (int r = r0; r < r0 + 32; ++r) {
        float v = x[(size_t)r * 384 + f];
        s += v; s2 += v * v;
    }
    atomicAdd(&acc[f], s);
    atomicAdd(&acc[384 + f], s2);
}

// ---------------------------------------------------------------------------
// K2b: finalize BN -> per-feature affine  y = x*A + C
// ---------------------------------------------------------------------------
__global__ void k_bnfinal(const float* __restrict__ acc,
                          const float* __restrict__ gamma,
                          const float* __restrict__ beta,
                          float* __restrict__ A, float* __restrict__ C) {
    int f = threadIdx.x;
    if (f < 384) {
        const float inv_b = 1.0f / (float)B_SZ;
        float mean = acc[f] * inv_b;
        float var  = acc[384 + f] * inv_b - mean * mean;
        float a = gamma[f] * rsqrtf(var + 1e-5f);
        A[f] = a;
        C[f] = beta[f] - mean * a;
    }
}

// ---------------------------------------------------------------------------
// K3: fused MLP. 8 rows per 256-thread block (grid 512 -> 2 blocks/CU).
// Loop-swapped: thread (rr=tid&7, og=tid>>3) keeps 7 independent accumulators
// for outputs o=og+32k; per f4-step: 1 LDS x-load (reused x7) + 7 independent
// coalesced global W loads -> deep ILP instead of one serial chain.
// ---------------------------------------------------------------------------
__global__ __launch_bounds__(256) void k_mlp(
    const float* __restrict__ x, const float* __restrict__ A, const float* __restrict__ C,
    const float* __restrict__ W1, const float* __restrict__ b1, const float* __restrict__ a1p,
    const float* __restrict__ W2, const float* __restrict__ b2, const float* __restrict__ a2p,
    const float* __restrict__ W3, const float* __restrict__ b3,
    float* __restrict__ out)
{
    const int r0 = blockIdx.x * 8;
    const int tid = threadIdx.x;
    const int rr = tid & 7, og = tid >> 3;        // 8 rows x 32 out-groups
    __shared__ __align__(16) float xs[8][388];    // stride 388: rr*4 mod 32 distinct banks
    __shared__ __align__(16) float h1[8][204];    // stride 204: rr*12 mod 32 distinct
    __shared__ __align__(16) float h2[8][84];     // stride 84:  rr*20 mod 32 distinct

    // load 8 rows of x (float4), apply BN affine during load
    {
        const float4* xg = (const float4*)(x + (size_t)r0 * 384);
        const float4* A4 = (const float4*)A;
        const float4* C4 = (const float4*)C;
        for (int e = tid; e < 8 * 96; e += 256) {
            int rr2 = e / 96, f4 = e - rr2 * 96;
            float4 v = xg[e], a = A4[f4], c = C4[f4];
            v.x = v.x * a.x + c.x; v.y = v.y * a.y + c.y;
            v.z = v.z * a.z + c.z; v.w = v.w * a.w + c.w;
            ((float4*)&xs[rr2][0])[f4] = v;
        }
    }
    __syncthreads();

    const float a1 = a1p[0], a2 = a2p[0];

    // ---- layer 1: 384 -> 200 ----
    {
        float acc[7] = {0.f, 0.f, 0.f, 0.f, 0.f, 0.f, 0.f};
        const float4* wp[7];
        #pragma unroll
        for (int k = 0; k < 7; ++k) {
            int o = og + 32 * k;
            wp[k] = (o < 200) ? (const float4*)(W1 + (size_t)o * 384) : (const float4*)W1;
        }
        const float4* xr = (const float4*)&xs[rr][0];
        #pragma unroll 2
        for (int f4 = 0; f4 < 96; ++f4) {
            float4 xv = xr[f4];
            #pragma unroll
            for (int k = 0; k < 7; ++k) {
                if (og + 32 * k < 200) {          // wave-uniform guard
                    float4 w = wp[k][f4];
                    acc[k] += w.x * xv.x + w.y * xv.y + w.z * xv.z + w.w * xv.w;
                }
            }
        }
        #pragma unroll
        for (int k = 0; k < 7; ++k) {
            int o = og + 32 * k;
            if (o < 200) {
                float s = acc[k] + b1[o];
                h1[rr][o] = (s >= 0.f) ? s : a1 * s;
            }
        }
    }
    __syncthreads();

    // ---- layer 2: 200 -> 80 ----
    {
        float acc[3] = {0.f, 0.f, 0.f};
        const float4* wp[3];
        #pragma unroll
        for (int k = 0; k < 3; ++k) {
            int o = og + 32 * k;
            wp[k] = (o < 80) ? (const float4*)(W2 + (size_t)o * 200) : (const float4*)W2;
        }
        const float4* hr = (const float4*)&h1[rr][0];
        #pragma unroll 2
        for (int f4 = 0; f4 < 50; ++f4) {
            float4 xv = hr[f4];
            #pragma unroll
            for (int k = 0; k < 3; ++k) {
                if (og + 32 * k < 80) {           // wave-uniform guard
                    float4 w = wp[k][f4];
                    acc[k] += w.x * xv.x + w.y * xv.y + w.z * xv.z + w.w * xv.w;
                }
            }
        }
        #pragma unroll
        for (int k = 0; k < 3; ++k) {
            int o = og + 32 * k;
            if (o < 80) {
                float s = acc[k] + b2[o];
                h2[rr][o] = (s >= 0.f) ? s : a2 * s;
            }
        }
    }
    __syncthreads();

    // ---- layer 3: 80 -> 2, softmax ----
    if (tid < 8) {
        float l0 = b3[0], l1 = b3[1];
        #pragma unroll 8
        for (int f = 0; f < 80; ++f) {
            float h = h2[tid][f];
            l0 += h * W3[f];
            l1 += h * W3[80 + f];
        }
        float m = fmaxf(l0, l1);
        float e0 = expf(l0 - m), e1 = expf(l1 - m);
        float inv = 1.0f / (e0 + e1);
        out[(size_t)(r0 + tid) * 2 + 0] = e0 * inv;
        out[(size_t)(r0 + tid) * 2 + 1] = e1 * inv;
    }
}

// ---------------------------------------------------------------------------
extern "C" void kernel_launch(void* const* d_in, const int* in_sizes, int n_in,
                              void* d_out, int out_size, void* d_ws, size_t ws_size,
                              hipStream_t stream) {
    const int*   user      = (const int*)  d_in[0];
    const int*   item      = (const int*)  d_in[1];
    const int*   history   = (const int*)  d_in[2];
    /* d_in[3] = length (unused: derived from history zeros, matching ref) */
    const int*   cate_list = (const int*)  d_in[4];
    const float* user_W    = (const float*)d_in[5];
    const float* item_W    = (const float*)d_in[6];
    const float* cate_W    = (const float*)d_in[7];
    const float* gamma     = (const float*)d_in[8];
    const float* beta      = (const float*)d_in[9];
    const float* W1        = (const float*)d_in[10];
    const float* b1        = (const float*)d_in[11];
    const float* a1        = (const float*)d_in[12];
    const float* W2        = (const float*)d_in[13];
    const float* b2        = (const float*)d_in[14];
    const float* a2        = (const float*)d_in[15];
    const float* W3        = (const float*)d_in[16];
    const float* b3        = (const float*)d_in[17];
    float* out = (float*)d_out;

    // workspace layout (floats): [0..3] first_bad(int)+pad, [16..783] acc,
    // [784..1167] A, [1168..1551] C, [1552..] x[4096*384]
    int*   first_bad = (int*)d_ws;
    float* acc = (float*)d_ws + 16;
    float* A   = acc + 768;
    float* C   = A + 384;
    float* x   = C + 384;

    hipLaunchKernelGGL(k_init,     dim3(1),    dim3(768), 0, stream, first_bad, acc);
    hipLaunchKernelGGL(k_firstbad, dim3(16),   dim3(256), 0, stream, history, first_bad);
    hipLaunchKernelGGL(k_pool,     dim3(B_SZ), dim3(256), 0, stream,
                       user, item, history, cate_list, user_W, item_W, cate_W,
                       first_bad, x);
    hipLaunchKernelGGL(k_bnstats,  dim3(128),  dim3(384), 0, stream, x, acc);
    hipLaunchKernelGGL(k_bnfinal,  dim3(1),    dim3(384), 0, stream, acc, gamma, beta, A, C);
    hipLaunchKernelGGL(k_mlp,      dim3(B_SZ/8), dim3(256), 0, stream,
                       x, A, C, W1, b1, a1, W2, b2, a2, W3, b3, out);
}

// Round 3
// 182.860 us; speedup vs baseline: 1.4947x; 1.3714x over previous
//
#include <hip/hip_runtime.h>
#include <hip/hip_bf16.h>

#define B_SZ 4096
#define L_SZ 200

typedef __bf16 bf16x8 __attribute__((ext_vector_type(8)));
typedef float  f32x4  __attribute__((ext_vector_type(4)));

static __device__ inline unsigned short bfbits(float f) {
    return __builtin_bit_cast(unsigned short, (__bf16)f);
}

// ---------------------------------------------------------------------------
// K0: init workspace accumulators (ws is poisoned 0xAA before every launch)
// ---------------------------------------------------------------------------
__global__ void k_init(int* __restrict__ first_bad, float* __restrict__ acc) {
    int t = threadIdx.x;
    if (t == 0) first_bad[0] = B_SZ;
    if (t < 768) acc[t] = 0.f;
}

// ---------------------------------------------------------------------------
// K0b: row-halt semantics — first row b whose history[b][0]==0 halts the loop
// ---------------------------------------------------------------------------
__global__ void k_firstbad(const int* __restrict__ history, int* __restrict__ first_bad) {
    int b = threadIdx.x + blockIdx.x * blockDim.x;
    if (b < B_SZ && history[(size_t)b * L_SZ] == 0) atomicMin(first_bad, b);
}

// ---------------------------------------------------------------------------
// K0c: pre-swizzle W1/W2 (fp32) into bf16 MFMA B-fragment order.
// Fragment chunk (oT,kS) = 64 lanes x 8 bf16: lane holds W[o=oT*16+(lane&15)]
// [k=kS*32+(lane>>4)*8+j], j=0..7.  -> k_mlp B-loads are lane-contiguous 1KB.
// W1: 13 oT x 12 kS (o>=200 zero-padded). W2: 5 oT x 7 kS (k>=200 zero-padded).
// ---------------------------------------------------------------------------
__global__ __launch_bounds__(64) void k_wfrag(const float* __restrict__ W1,
                                              const float* __restrict__ W2,
                                              ushort* __restrict__ W1f,
                                              ushort* __restrict__ W2f) {
    const int bid = blockIdx.x, lane = threadIdx.x;
    const int nr = lane & 15, quad = lane >> 4;
    ushort v[8];
    if (bid < 156) {                       // W1: 13*12 chunks
        const int oT = bid / 12, kS = bid % 12;
        const int o = oT * 16 + nr;
        #pragma unroll
        for (int j = 0; j < 8; ++j) {
            int k = kS * 32 + quad * 8 + j;
            v[j] = (o < 200) ? bfbits(W1[(size_t)o * 384 + k]) : (ushort)0;
        }
        ushort* dst = W1f + ((size_t)bid * 64 + lane) * 8;
        *(ushort4*)(dst)     = make_ushort4(v[0], v[1], v[2], v[3]);
        *(ushort4*)(dst + 4) = make_ushort4(v[4], v[5], v[6], v[7]);
    } else {                               // W2: 5*7 chunks
        const int idx = bid - 156;
        const int oT = idx / 7, kS = idx % 7;
        const int o = oT * 16 + nr;        // < 80 always
        #pragma unroll
        for (int j = 0; j < 8; ++j) {
            int k = kS * 32 + quad * 8 + j;
            v[j] = (k < 200) ? bfbits(W2[(size_t)o * 200 + k]) : (ushort)0;
        }
        ushort* dst = W2f + ((size_t)idx * 64 + lane) * 8;
        *(ushort4*)(dst)     = make_ushort4(v[0], v[1], v[2], v[3]);
        *(ushort4*)(dst + 4) = make_ushort4(v[4], v[5], v[6], v[7]);
    }
}

// ---------------------------------------------------------------------------
// K1: per-row masked mean-pool of concat(item_emb, cate_emb) + build x[b,384]
// ---------------------------------------------------------------------------
__global__ __launch_bounds__(256) void k_pool(
    const int* __restrict__ user, const int* __restrict__ item,
    const int* __restrict__ history, const int* __restrict__ cate_list,
    const float* __restrict__ user_W, const float* __restrict__ item_W,
    const float* __restrict__ cate_W, const int* __restrict__ first_bad,
    float* __restrict__ x)
{
    const int b = blockIdx.x;
    const int tid = threadIdx.x;
    __shared__ int sh_item[L_SZ];
    __shared__ int sh_cid[L_SZ];
    __shared__ int s_fz;
    __shared__ __align__(16) float red[8][128];
    if (tid == 0) s_fz = L_SZ;
    __syncthreads();
    if (tid < L_SZ) {
        int h = history[(size_t)b * L_SZ + tid];
        sh_item[tid] = h;
        if (tid >= 1 && h == 0) atomicMin(&s_fz, tid);
        sh_cid[tid] = cate_list[h];
    }
    __syncthreads();
    const bool active = (b < first_bad[0]);
    const int valid = active ? s_fz : 0;
    const float inv_cnt = 1.0f / (float)max(valid, 1);

    const int group = tid >> 5, lane = tid & 31;
    const int sub = lane >> 4, q = lane & 15;
    const float* tab = (sub == 0) ? item_W : cate_W;
    const int*   ids = (sub == 0) ? sh_item : sh_cid;
    float4 acc = make_float4(0.f, 0.f, 0.f, 0.f);
    int l = group;
    for (; l + 8 < valid; l += 16) {
        int id0 = ids[l], id1 = ids[l + 8];
        float4 v0 = ((const float4*)(tab + (size_t)id0 * 64))[q];
        float4 v1 = ((const float4*)(tab + (size_t)id1 * 64))[q];
        acc.x += v0.x + v1.x; acc.y += v0.y + v1.y;
        acc.z += v0.z + v1.z; acc.w += v0.w + v1.w;
    }
    if (l < valid) {
        int id = ids[l];
        float4 v = ((const float4*)(tab + (size_t)id * 64))[q];
        acc.x += v.x; acc.y += v.y; acc.z += v.z; acc.w += v.w;
    }
    *((float4*)&red[group][lane * 4]) = acc;
    __syncthreads();

    float* xrow = x + (size_t)b * 384;
    if (tid < 128) {
        float s = 0.f;
        #pragma unroll
        for (int g = 0; g < 8; ++g) s += red[g][tid];
        xrow[256 + tid] = s * inv_cnt;
        xrow[tid] = user_W[(size_t)user[b] * 128 + tid];
    } else if (tid < 192) {
        int f = tid - 128;
        xrow[128 + f] = item_W[(size_t)item[b] * 64 + f];
    } else {
        int f = tid - 192;
        xrow[192 + f] = cate_W[(size_t)cate_list[item[b]] * 64 + f];
    }
}

// ---------------------------------------------------------------------------
// K2a: BN batch statistics partial sums
// ---------------------------------------------------------------------------
__global__ __launch_bounds__(384) void k_bnstats(const float* __restrict__ x,
                                                 float* __restrict__ acc) {
    const int f = threadIdx.x;
    const int r0 = blockIdx.x * 32;
    float s = 0.f, s2 = 0.f;
    for (int r = r0; r < r0 + 32; ++r) {
        float v = x[(size_t)r * 384 + f];
        s += v; s2 += v * v;
    }
    atomicAdd(&acc[f], s);
    atomicAdd(&acc[384 + f], s2);
}

// ---------------------------------------------------------------------------
// K2b: finalize BN -> per-feature affine  y = x*A + C
// ---------------------------------------------------------------------------
__global__ void k_bnfinal(const float* __restrict__ acc,
                          const float* __restrict__ gamma,
                          const float* __restrict__ beta,
                          float* __restrict__ A, float* __restrict__ C) {
    int f = threadIdx.x;
    if (f < 384) {
        const float inv_b = 1.0f / (float)B_SZ;
        float mean = acc[f] * inv_b;
        float var  = acc[384 + f] * inv_b - mean * mean;
        float a = gamma[f] * rsqrtf(var + 1e-5f);
        A[f] = a;
        C[f] = beta[f] - mean * a;
    }
}

// ---------------------------------------------------------------------------
// K3: fused MFMA MLP. 16 rows/block, 256 blocks, 4 waves.
// L1: M=16,K=384(12 kS),N=208(13 oT, split over waves). bf16 16x16x32 MFMA.
// A-frags: ds_read_b128 from padded bf16 xs (conflict-free: lanes0-7 span all
// 32 banks). B-frags: coalesced 1KB wave loads from pre-swizzled W1f/W2f.
// Bias folded into acc init (C/D col = lane&15 = out dim). h1 -> LDS bf16
// (A-layout for L2). L3+softmax fp32.
// ---------------------------------------------------------------------------
#define XS_STRIDE 392   // bf16 elems/row: 384 + 8 pad (784B, 16B-aligned, 2-way max)
#define H1_STRIDE 232   // bf16 elems/row: 224 + 8 pad (464B, 16B-aligned)

__global__ __launch_bounds__(256) void k_mlp(
    const float* __restrict__ x, const float* __restrict__ A, const float* __restrict__ C,
    const ushort* __restrict__ W1f, const float* __restrict__ b1, const float* __restrict__ a1p,
    const ushort* __restrict__ W2f, const float* __restrict__ b2, const float* __restrict__ a2p,
    const float* __restrict__ W3, const float* __restrict__ b3,
    float* __restrict__ out)
{
    const int r0 = blockIdx.x * 16;
    const int tid = threadIdx.x;
    const int lane = tid & 63, wv = tid >> 6;
    const int nr = lane & 15, quad = lane >> 4;

    __shared__ __align__(16) __bf16 xs[16 * XS_STRIDE];
    __shared__ __align__(16) __bf16 h1s[16 * H1_STRIDE];
    __shared__ __align__(16) float  h2s[16][84];

    // ---- stage x: 16x384 fp32 -> BN affine -> bf16 LDS (coalesced) ----
    {
        const float4* xg = (const float4*)(x + (size_t)r0 * 384);
        const float4* A4 = (const float4*)A;
        const float4* C4 = (const float4*)C;
        for (int e = tid; e < 16 * 96; e += 256) {
            int rr = e / 96, f4 = e - rr * 96;
            float4 v = xg[e], a = A4[f4], c = C4[f4];
            ushort4 p = make_ushort4(bfbits(v.x * a.x + c.x), bfbits(v.y * a.y + c.y),
                                     bfbits(v.z * a.z + c.z), bfbits(v.w * a.w + c.w));
            *(ushort4*)&xs[rr * XS_STRIDE + f4 * 4] = p;
        }
        // zero h1 padding cols 200..223 (read by L2 kS=6; W2f also 0 there,
        // but keep LDS clean of NaN garbage)
        if (tid < 192) {
            int rr = tid / 12, c4 = tid - rr * 12;
            *(uint*)((char*)&h1s[rr * H1_STRIDE] + 400 + c4 * 4) = 0u;
        }
    }
    __syncthreads();

    const float a1 = a1p[0], a2 = a2p[0];

    // ---- layer 1: wave wv owns oT = wv, wv+4, wv+8, wv+12(<13) ----
    {
        f32x4 acc[4];
        #pragma unroll
        for (int i = 0; i < 4; ++i) {
            int o = (wv + 4 * i) * 16 + nr;
            float bias = (wv + 4 * i < 13 && o < 200) ? b1[o] : 0.f;
            acc[i] = (f32x4){bias, bias, bias, bias};
        }
        for (int kS = 0; kS < 12; ++kS) {
            bf16x8 af = *(const bf16x8*)&xs[nr * XS_STRIDE + kS * 32 + quad * 8];
            bf16x8 bfr[4];
            #pragma unroll
            for (int i = 0; i < 4; ++i)
                if (wv + 4 * i < 13)
                    bfr[i] = *(const bf16x8*)(W1f + (((size_t)(wv + 4 * i) * 12 + kS) * 64 + lane) * 8);
            #pragma unroll
            for (int i = 0; i < 4; ++i)
                if (wv + 4 * i < 13)
                    acc[i] = __builtin_amdgcn_mfma_f32_16x16x32_bf16(af, bfr[i], acc[i], 0, 0, 0);
        }
        // epilogue: prelu -> bf16 h1s  (C/D: row = quad*4+reg, col = oT*16+nr)
        #pragma unroll
        for (int i = 0; i < 4; ++i) {
            if (wv + 4 * i < 13) {
                int o = (wv + 4 * i) * 16 + nr;
                if (o < 208) {
                    #pragma unroll
                    for (int r = 0; r < 4; ++r) {
                        float s = acc[i][r];
                        s = (s >= 0.f) ? s : a1 * s;
                        h1s[(quad * 4 + r) * H1_STRIDE + o] = (__bf16)s;
                    }
                }
            }
        }
    }
    __syncthreads();

    // ---- layer 2: wave wv owns oT2 = wv (+4 for wave 0); N=80=5x16, K=224 ----
    {
        f32x4 acc[2];
        #pragma unroll
        for (int i = 0; i < 2; ++i) {
            int oT = wv + 4 * i;
            float bias = (oT < 5) ? b2[oT * 16 + nr] : 0.f;
            acc[i] = (f32x4){bias, bias, bias, bias};
        }
        for (int kS = 0; kS < 7; ++kS) {
            bf16x8 af = *(const bf16x8*)&h1s[nr * H1_STRIDE + kS * 32 + quad * 8];
            bf16x8 bfr[2];
            #pragma unroll
            for (int i = 0; i < 2; ++i)
                if (wv + 4 * i < 5)
                    bfr[i] = *(const bf16x8*)(W2f + (((size_t)(wv + 4 * i) * 7 + kS) * 64 + lane) * 8);
            #pragma unroll
            for (int i = 0; i < 2; ++i)
                if (wv + 4 * i < 5)
                    acc[i] = __builtin_amdgcn_mfma_f32_16x16x32_bf16(af, bfr[i], acc[i], 0, 0, 0);
        }
        #pragma unroll
        for (int i = 0; i < 2; ++i) {
            if (wv + 4 * i < 5) {
                int o = (wv + 4 * i) * 16 + nr;
                #pragma unroll
                for (int r = 0; r < 4; ++r) {
                    float s = acc[i][r];
                    h2s[quad * 4 + r][o] = (s >= 0.f) ? s : a2 * s;
                }
            }
        }
    }
    __syncthreads();

    // ---- layer 3: 80 -> 2, softmax (fp32) ----
    if (tid < 16) {
        float l0 = b3[0], l1 = b3[1];
        #pragma unroll 8
        for (int f = 0; f < 80; ++f) {
            float h = h2s[tid][f];
            l0 += h * W3[f];
            l1 += h * W3[80 + f];
        }
        float m = fmaxf(l0, l1);
        float e0 = expf(l0 - m), e1 = expf(l1 - m);
        float inv = 1.0f / (e0 + e1);
        out[(size_t)(r0 + tid) * 2 + 0] = e0 * inv;
        out[(size_t)(r0 + tid) * 2 + 1] = e1 * inv;
    }
}

// ---------------------------------------------------------------------------
extern "C" void kernel_launch(void* const* d_in, const int* in_sizes, int n_in,
                              void* d_out, int out_size, void* d_ws, size_t ws_size,
                              hipStream_t stream) {
    const int*   user      = (const int*)  d_in[0];
    const int*   item      = (const int*)  d_in[1];
    const int*   history   = (const int*)  d_in[2];
    const int*   cate_list = (const int*)  d_in[4];
    const float* user_W    = (const float*)d_in[5];
    const float* item_W    = (const float*)d_in[6];
    const float* cate_W    = (const float*)d_in[7];
    const float* gamma     = (const float*)d_in[8];
    const float* beta      = (const float*)d_in[9];
    const float* W1        = (const float*)d_in[10];
    const float* b1        = (const float*)d_in[11];
    const float* a1        = (const float*)d_in[12];
    const float* W2        = (const float*)d_in[13];
    const float* b2        = (const float*)d_in[14];
    const float* a2        = (const float*)d_in[15];
    const float* W3        = (const float*)d_in[16];
    const float* b3        = (const float*)d_in[17];
    float* out = (float*)d_out;

    // ws layout (float offsets): 0 first_bad(int)+pad, 16 acc[768], 784 A[384],
    // 1168 C[384], 1552 x[4096*384], then W1f/W2f (bf16 fragment buffers)
    int*   first_bad = (int*)d_ws;
    float* acc = (float*)d_ws + 16;
    float* A   = acc + 768;
    float* C   = A + 384;
    float* x   = C + 384;
    ushort* W1f = (ushort*)(x + (size_t)B_SZ * 384);           // 156*64*8 ushorts
    ushort* W2f = W1f + (size_t)156 * 64 * 8;                  // 35*64*8 ushorts

    hipLaunchKernelGGL(k_init,     dim3(1),    dim3(768), 0, stream, first_bad, acc);
    hipLaunchKernelGGL(k_firstbad, dim3(16),   dim3(256), 0, stream, history, first_bad);
    hipLaunchKernelGGL(k_wfrag,    dim3(191),  dim3(64),  0, stream, W1, W2, W1f, W2f);
    hipLaunchKernelGGL(k_pool,     dim3(B_SZ), dim3(256), 0, stream,
                       user, item, history, cate_list, user_W, item_W, cate_W,
                       first_bad, x);
    hipLaunchKernelGGL(k_bnstats,  dim3(128),  dim3(384), 0, stream, x, acc);
    hipLaunchKernelGGL(k_bnfinal,  dim3(1),    dim3(384), 0, stream, acc, gamma, beta, A, C);
    hipLaunchKernelGGL(k_mlp,      dim3(B_SZ/16), dim3(256), 0, stream,
                       x, A, C, W1f, b1, a1, W2f, b2, a2, W3, b3, out);
}

// Round 4
// 180.984 us; speedup vs baseline: 1.5102x; 1.0104x over previous
//
#include <hip/hip_runtime.h>
#include <hip/hip_bf16.h>

#define B_SZ 4096
#define L_SZ 200

typedef __bf16 bf16x8 __attribute__((ext_vector_type(8)));
typedef float  f32x4  __attribute__((ext_vector_type(4)));

static __device__ inline unsigned short bfbits(float f) {
    return __builtin_bit_cast(unsigned short, (__bf16)f);
}
static __device__ inline float bf2f(unsigned short u) {
    return __builtin_bit_cast(float, (unsigned int)u << 16);
}

// ---------------------------------------------------------------------------
// K0: one-block prep: zero BN accumulators + compute first_bad (row-halt
// semantics: first row b with history[b][0]==0) via block-local reduction.
// ---------------------------------------------------------------------------
__global__ __launch_bounds__(1024) void k_prep(const int* __restrict__ history,
                                               int* __restrict__ first_bad,
                                               float* __restrict__ acc) {
    const int tid = threadIdx.x;
    if (tid < 768) acc[tid] = 0.f;
    int m = B_SZ;
    for (int b = tid; b < B_SZ; b += 1024)
        if (history[(size_t)b * L_SZ] == 0) m = min(m, b);
    __shared__ int red[1024];
    red[tid] = m;
    __syncthreads();
    for (int s = 512; s > 0; s >>= 1) {
        if (tid < s) red[tid] = min(red[tid], red[tid + s]);
        __syncthreads();
    }
    if (tid == 0) first_bad[0] = red[0];
}

// ---------------------------------------------------------------------------
// K0c: pre-swizzle W1/W2 (fp32) into bf16 MFMA B-fragment order.
// Chunk (oT,kS) = 64 lanes x 8 bf16: lane holds W[o=oT*16+(lane&15)]
// [k=kS*32+(lane>>4)*8+j].  W1: 13x12 (o>=200 zero). W2: 5x7 (k>=200 zero).
// ---------------------------------------------------------------------------
__global__ __launch_bounds__(64) void k_wfrag(const float* __restrict__ W1,
                                              const float* __restrict__ W2,
                                              ushort* __restrict__ W1f,
                                              ushort* __restrict__ W2f) {
    const int bid = blockIdx.x, lane = threadIdx.x;
    const int nr = lane & 15, quad = lane >> 4;
    ushort v[8];
    if (bid < 156) {
        const int oT = bid / 12, kS = bid % 12;
        const int o = oT * 16 + nr;
        #pragma unroll
        for (int j = 0; j < 8; ++j) {
            int k = kS * 32 + quad * 8 + j;
            v[j] = (o < 200) ? bfbits(W1[(size_t)o * 384 + k]) : (ushort)0;
        }
        ushort* dst = W1f + ((size_t)bid * 64 + lane) * 8;
        *(ushort4*)(dst)     = make_ushort4(v[0], v[1], v[2], v[3]);
        *(ushort4*)(dst + 4) = make_ushort4(v[4], v[5], v[6], v[7]);
    } else {
        const int idx = bid - 156;
        const int oT = idx / 7, kS = idx % 7;
        const int o = oT * 16 + nr;
        #pragma unroll
        for (int j = 0; j < 8; ++j) {
            int k = kS * 32 + quad * 8 + j;
            v[j] = (k < 200) ? bfbits(W2[(size_t)o * 200 + k]) : (ushort)0;
        }
        ushort* dst = W2f + ((size_t)idx * 64 + lane) * 8;
        *(ushort4*)(dst)     = make_ushort4(v[0], v[1], v[2], v[3]);
        *(ushort4*)(dst + 4) = make_ushort4(v[4], v[5], v[6], v[7]);
    }
}

// ---------------------------------------------------------------------------
// K1: per-row masked mean-pool + build xb[b,384] (bf16, row stride 384)
// ---------------------------------------------------------------------------
__global__ __launch_bounds__(256) void k_pool(
    const int* __restrict__ user, const int* __restrict__ item,
    const int* __restrict__ history, const int* __restrict__ cate_list,
    const float* __restrict__ user_W, const float* __restrict__ item_W,
    const float* __restrict__ cate_W, const int* __restrict__ first_bad,
    ushort* __restrict__ xb)
{
    const int b = blockIdx.x;
    const int tid = threadIdx.x;
    __shared__ int sh_item[L_SZ];
    __shared__ int sh_cid[L_SZ];
    __shared__ int s_fz;
    __shared__ __align__(16) float red[8][128];
    if (tid == 0) s_fz = L_SZ;
    __syncthreads();
    if (tid < L_SZ) {
        int h = history[(size_t)b * L_SZ + tid];
        sh_item[tid] = h;
        if (tid >= 1 && h == 0) atomicMin(&s_fz, tid);
        sh_cid[tid] = cate_list[h];
    }
    __syncthreads();
    const bool active = (b < first_bad[0]);
    const int valid = active ? s_fz : 0;
    const float inv_cnt = 1.0f / (float)max(valid, 1);

    const int group = tid >> 5, lane = tid & 31;
    const int sub = lane >> 4, q = lane & 15;
    const float* tab = (sub == 0) ? item_W : cate_W;
    const int*   ids = (sub == 0) ? sh_item : sh_cid;
    float4 acc = make_float4(0.f, 0.f, 0.f, 0.f);
    int l = group;
    for (; l + 8 < valid; l += 16) {
        int id0 = ids[l], id1 = ids[l + 8];
        float4 v0 = ((const float4*)(tab + (size_t)id0 * 64))[q];
        float4 v1 = ((const float4*)(tab + (size_t)id1 * 64))[q];
        acc.x += v0.x + v1.x; acc.y += v0.y + v1.y;
        acc.z += v0.z + v1.z; acc.w += v0.w + v1.w;
    }
    if (l < valid) {
        int id = ids[l];
        float4 v = ((const float4*)(tab + (size_t)id * 64))[q];
        acc.x += v.x; acc.y += v.y; acc.z += v.z; acc.w += v.w;
    }
    *((float4*)&red[group][lane * 4]) = acc;
    __syncthreads();

    ushort* xrow = xb + (size_t)b * 384;
    if (tid < 128) {
        float s = 0.f;
        #pragma unroll
        for (int g = 0; g < 8; ++g) s += red[g][tid];
        xrow[256 + tid] = bfbits(s * inv_cnt);
        xrow[tid] = bfbits(user_W[(size_t)user[b] * 128 + tid]);
    } else if (tid < 192) {
        int f = tid - 128;
        xrow[128 + f] = bfbits(item_W[(size_t)item[b] * 64 + f]);
    } else {
        int f = tid - 192;
        xrow[192 + f] = bfbits(cate_W[(size_t)cate_list[item[b]] * 64 + f]);
    }
}

// ---------------------------------------------------------------------------
// K2: BN batch statistics partial sums (bf16 x, coalesced column ownership)
// ---------------------------------------------------------------------------
__global__ __launch_bounds__(384) void k_bnstats(const ushort* __restrict__ xb,
                                                 float* __restrict__ acc) {
    const int f = threadIdx.x;
    const int r0 = blockIdx.x * 32;
    float s = 0.f, s2 = 0.f;
    for (int r = r0; r < r0 + 32; ++r) {
        float v = bf2f(xb[(size_t)r * 384 + f]);
        s += v; s2 += v * v;
    }
    atomicAdd(&acc[f], s);
    atomicAdd(&acc[384 + f], s2);
}

// ---------------------------------------------------------------------------
// K3a: layer 1 — wave-autonomous MFMA tiles, no inter-wave dependency.
// wave wid -> (mT = wid/13, oT = wid%13); 3328 waves, 832 blocks.
// A-frag straight from global bf16 xb (16 fully-consumed 64B lines / load),
// BN affine applied in-register; B-frag coalesced from W1f; prelu -> h1b bf16
// (row stride 224, cols 200..223 zeroed by the oT==12 wave).
// Inlined BN-finalize per block (acc -> A,C in LDS) deletes k_bnfinal.
// ---------------------------------------------------------------------------
__global__ __launch_bounds__(256) void k_l1(
    const ushort* __restrict__ xb, const float* __restrict__ accv,
    const float* __restrict__ gamma, const float* __restrict__ beta,
    const ushort* __restrict__ W1f, const float* __restrict__ b1,
    const float* __restrict__ a1p, ushort* __restrict__ h1b)
{
    __shared__ float As[384], Cs[384];
    const int tid = threadIdx.x;
    for (int f = tid; f < 384; f += 256) {
        const float inv_b = 1.0f / (float)B_SZ;
        float mean = accv[f] * inv_b;
        float var  = accv[384 + f] * inv_b - mean * mean;
        float a = gamma[f] * rsqrtf(var + 1e-5f);
        As[f] = a;
        Cs[f] = beta[f] - mean * a;
    }
    __syncthreads();

    const int lane = tid & 63, wv = tid >> 6;
    const int nr = lane & 15, quad = lane >> 4;
    const int wid = blockIdx.x * 4 + wv;
    const int mT = wid / 13, oT = wid - mT * 13;
    const int o = oT * 16 + nr;
    const float a1 = a1p[0];

    float bias = (o < 200) ? b1[o] : 0.f;
    f32x4 acc = {bias, bias, bias, bias};
    const ushort* xrow = xb + (size_t)(mT * 16 + nr) * 384;

    for (int kS = 0; kS < 12; ++kS) {
        const int kc = kS * 32 + quad * 8;
        bf16x8 a8 = *(const bf16x8*)(xrow + kc);
        float4 A0 = *(const float4*)&As[kc],     A1 = *(const float4*)&As[kc + 4];
        float4 C0 = *(const float4*)&Cs[kc],     C1 = *(const float4*)&Cs[kc + 4];
        bf16x8 w;
        w[0] = (__bf16)((float)a8[0] * A0.x + C0.x);
        w[1] = (__bf16)((float)a8[1] * A0.y + C0.y);
        w[2] = (__bf16)((float)a8[2] * A0.z + C0.z);
        w[3] = (__bf16)((float)a8[3] * A0.w + C0.w);
        w[4] = (__bf16)((float)a8[4] * A1.x + C1.x);
        w[5] = (__bf16)((float)a8[5] * A1.y + C1.y);
        w[6] = (__bf16)((float)a8[6] * A1.z + C1.z);
        w[7] = (__bf16)((float)a8[7] * A1.w + C1.w);
        bf16x8 bfr = *(const bf16x8*)(W1f + (((size_t)oT * 12 + kS) * 64 + lane) * 8);
        acc = __builtin_amdgcn_mfma_f32_16x16x32_bf16(w, bfr, acc, 0, 0, 0);
    }

    #pragma unroll
    for (int r = 0; r < 4; ++r) {
        int row = mT * 16 + quad * 4 + r;
        float s = acc[r];
        s = (s >= 0.f) ? s : a1 * s;
        h1b[(size_t)row * 224 + o] = bfbits(s);
        if (oT == 12) h1b[(size_t)row * 224 + o + 16] = 0;   // zero pad cols 208..223
    }
}

// ---------------------------------------------------------------------------
// K3b: layers 2+3 — one wave per 16-row tile, no LDS, no barriers.
// L2: K=224 (7 kS), N=80 (5 oT, all owned by the wave). Then prelu, 80->2
// dot folded via shfl-xor butterfly over the nr group, softmax, store.
// ---------------------------------------------------------------------------
__global__ __launch_bounds__(256) void k_l23(
    const ushort* __restrict__ h1b, const ushort* __restrict__ W2f,
    const float* __restrict__ b2, const float* __restrict__ a2p,
    const float* __restrict__ W3, const float* __restrict__ b3,
    float* __restrict__ out)
{
    const int tid = threadIdx.x;
    const int lane = tid & 63, wv = tid >> 6;
    const int nr = lane & 15, quad = lane >> 4;
    const int mT = blockIdx.x * 4 + wv;
    const float a2 = a2p[0];

    f32x4 acc[5];
    #pragma unroll
    for (int i = 0; i < 5; ++i) {
        float bb = b2[i * 16 + nr];
        acc[i] = (f32x4){bb, bb, bb, bb};
    }
    const ushort* hrow = h1b + (size_t)(mT * 16 + nr) * 224;
    for (int kS = 0; kS < 7; ++kS) {
        bf16x8 a8 = *(const bf16x8*)(hrow + kS * 32 + quad * 8);
        #pragma unroll
        for (int i = 0; i < 5; ++i) {
            bf16x8 bfr = *(const bf16x8*)(W2f + (((size_t)i * 7 + kS) * 64 + lane) * 8);
            acc[i] = __builtin_amdgcn_mfma_f32_16x16x32_bf16(a8, bfr, acc[i], 0, 0, 0);
        }
    }

    float w0[5], w1[5];
    #pragma unroll
    for (int i = 0; i < 5; ++i) {
        w0[i] = W3[i * 16 + nr];
        w1[i] = W3[80 + i * 16 + nr];
    }
    f32x4 p0 = {0.f, 0.f, 0.f, 0.f}, p1 = {0.f, 0.f, 0.f, 0.f};
    #pragma unroll
    for (int i = 0; i < 5; ++i) {
        #pragma unroll
        for (int r = 0; r < 4; ++r) {
            float s = acc[i][r];
            s = (s >= 0.f) ? s : a2 * s;
            p0[r] += s * w0[i];
            p1[r] += s * w1[i];
        }
    }
    #pragma unroll
    for (int m = 1; m < 16; m <<= 1) {
        #pragma unroll
        for (int r = 0; r < 4; ++r) {
            p0[r] += __shfl_xor(p0[r], m, 64);
            p1[r] += __shfl_xor(p1[r], m, 64);
        }
    }
    if (nr == 0) {
        float B0 = b3[0], B1 = b3[1];
        #pragma unroll
        for (int r = 0; r < 4; ++r) {
            float l0 = p0[r] + B0, l1 = p1[r] + B1;
            float mx = fmaxf(l0, l1);
            float e0 = expf(l0 - mx), e1 = expf(l1 - mx);
            float inv = 1.0f / (e0 + e1);
            int row = mT * 16 + quad * 4 + r;
            *(float2*)(out + (size_t)row * 2) = make_float2(e0 * inv, e1 * inv);
        }
    }
}

// ---------------------------------------------------------------------------
extern "C" void kernel_launch(void* const* d_in, const int* in_sizes, int n_in,
                              void* d_out, int out_size, void* d_ws, size_t ws_size,
                              hipStream_t stream) {
    const int*   user      = (const int*)  d_in[0];
    const int*   item      = (const int*)  d_in[1];
    const int*   history   = (const int*)  d_in[2];
    const int*   cate_list = (const int*)  d_in[4];
    const float* user_W    = (const float*)d_in[5];
    const float* item_W    = (const float*)d_in[6];
    const float* cate_W    = (const float*)d_in[7];
    const float* gamma     = (const float*)d_in[8];
    const float* beta      = (const float*)d_in[9];
    const float* W1        = (const float*)d_in[10];
    const float* b1        = (const float*)d_in[11];
    const float* a1        = (const float*)d_in[12];
    const float* W2        = (const float*)d_in[13];
    const float* b2        = (const float*)d_in[14];
    const float* a2        = (const float*)d_in[15];
    const float* W3        = (const float*)d_in[16];
    const float* b3        = (const float*)d_in[17];
    float* out = (float*)d_out;

    // ws byte layout (all 64B-aligned):
    //      0 first_bad (int)
    //     64 acc[768] fp32                (3072 B)
    //   3200 xb  [4096*384] bf16          (3,145,728 B)
    // 3148928 h1b [4096*224] bf16         (1,835,008 B)
    // 4983936 W1f [156*64*8] bf16         (159,744 B)
    // 5143680 W2f [35*64*8]  bf16         (35,840 B)
    char* ws = (char*)d_ws;
    int*    first_bad = (int*)   ws;
    float*  acc       = (float*)(ws + 64);
    ushort* xb        = (ushort*)(ws + 3200);
    ushort* h1b       = (ushort*)(ws + 3148928);
    ushort* W1f       = (ushort*)(ws + 4983936);
    ushort* W2f       = (ushort*)(ws + 5143680);

    hipLaunchKernelGGL(k_prep,    dim3(1),    dim3(1024), 0, stream, history, first_bad, acc);
    hipLaunchKernelGGL(k_wfrag,   dim3(191),  dim3(64),   0, stream, W1, W2, W1f, W2f);
    hipLaunchKernelGGL(k_pool,    dim3(B_SZ), dim3(256),  0, stream,
                       user, item, history, cate_list, user_W, item_W, cate_W,
                       first_bad, xb);
    hipLaunchKernelGGL(k_bnstats, dim3(128),  dim3(384),  0, stream, xb, acc);
    hipLaunchKernelGGL(k_l1,      dim3(832),  dim3(256),  0, stream,
                       xb, acc, gamma, beta, W1f, b1, a1, h1b);
    hipLaunchKernelGGL(k_l23,     dim3(64),   dim3(256),  0, stream,
                       h1b, W2f, b2, a2, W3, b3, out);
}